// Round 6
// baseline (741.241 us; speedup 1.0000x reference)
//
#include <hip/hip_runtime.h>
#include <cstdint>

#define E_EXP 8
#define BATCH 8192
#define D0 480
#define D1 512
#define D2 512
#define D3 363
#define KP 512      // padded per-expert K
#define N3PAD 384

typedef _Float16 f16x8 __attribute__((ext_vector_type(8)));
typedef float f32x4 __attribute__((ext_vector_type(4)));
typedef unsigned short u16;
typedef u16 u16x8 __attribute__((ext_vector_type(8)));

__device__ __forceinline__ u16 f2h(float f) {
    _Float16 h = (_Float16)f;
    return __builtin_bit_cast(u16, h);
}

// async global->LDS, 16B per lane; LDS dest = wave-uniform base + lane*16
__device__ __forceinline__ void async16(const u16* g, u16* s) {
    __builtin_amdgcn_global_load_lds(
        reinterpret_cast<const __attribute__((address_space(1))) void*>(
            reinterpret_cast<uintptr_t>(g)),
        reinterpret_cast<__attribute__((address_space(3))) void*>(
            reinterpret_cast<uintptr_t>(s)),
        16, 0, 0);
}

// W[e][o][i] fp32 -> wf[e][o][0..511] fp16, zero-padded in o (to OUTP) and i (to 512)
__device__ __forceinline__ void pack_seg(const float* __restrict__ src,
                                         u16* __restrict__ dst,
                                         int OUT_src, int OUTP, int IN_src) {
    int total = E_EXP * OUTP * 128;
    int in4 = IN_src >> 2;
    for (int idx = blockIdx.x * blockDim.x + threadIdx.x; idx < total;
         idx += gridDim.x * blockDim.x) {
        int e = idx / (OUTP * 128);
        int r = idx - e * OUTP * 128;
        int o = r >> 7;
        int k4 = r & 127;
        ushort4 w;
        if (o < OUT_src && k4 < in4) {
            const float4 v = *reinterpret_cast<const float4*>(
                src + ((size_t)e * OUT_src + o) * IN_src + (k4 << 2));
            w.x = f2h(v.x); w.y = f2h(v.y); w.z = f2h(v.z); w.w = f2h(v.w);
        } else {
            w.x = 0; w.y = 0; w.z = 0; w.w = 0;
        }
        *reinterpret_cast<ushort4*>(dst + ((size_t)e * OUTP + o) * KP + (k4 << 2)) = w;
    }
}

__global__ void pack_all(const float* __restrict__ W1, const float* __restrict__ W2,
                         const float* __restrict__ W3, u16* __restrict__ wf1,
                         u16* __restrict__ wf2, u16* __restrict__ wf3) {
    pack_seg(W1, wf1, 512, 512, D0);
    pack_seg(W2, wf2, 512, 512, D1);
    pack_seg(W3, wf3, D3, N3PAD, D2);
}

// x (8192x480 fp32) -> xp (8192x512 fp16, zero-padded)
__global__ void pad_x(const float* __restrict__ x, u16* __restrict__ xp) {
    int total = BATCH * 128;
    for (int idx = blockIdx.x * blockDim.x + threadIdx.x; idx < total;
         idx += gridDim.x * blockDim.x) {
        int b = idx >> 7, k4 = idx & 127;
        ushort4 w;
        if (k4 < 120) {
            const float4 v = *reinterpret_cast<const float4*>(
                x + (size_t)b * D0 + (k4 << 2));
            w.x = f2h(v.x); w.y = f2h(v.y); w.z = f2h(v.z); w.w = f2h(v.w);
        } else {
            w.x = 0; w.y = 0; w.z = 0; w.w = 0;
        }
        *reinterpret_cast<ushort4*>(xp + (size_t)b * KP + (k4 << 2)) = w;
    }
}

// Fused blended GEMM, 2-way expert split:
// P[sp][m][n] = sum_{e in 4-expert split sp} bl[e,m] * (A @ W_e^T)[m,n]
// A unscaled in LDS; blend applied in-register to the A-fragment (each lane's
// A-frag is a single row m). Tile 128x128, BK=64, nk=8; 512 thr = 8 waves (2m x 4n).
__global__ __launch_bounds__(512, 4) void gemm_fused(
    const u16* __restrict__ A, const u16* __restrict__ Bw,
    const float* __restrict__ blend, u16* __restrict__ P, int OUTP, int nbn) {
    __shared__ __align__(16) u16 S[40960];  // 80 KB: As 8192, Bs 4x8192
    u16* As = S;
    u16* Bs = S + 8192;
    const int tid = threadIdx.x;
    const int w = tid >> 6, lane = tid & 63;
    const int wm = w & 1, wn = w >> 1;
    const int q = lane >> 4, l15 = lane & 15;

    const int id = blockIdx.x;
    const int xcd = id & 7;
    const int j = id >> 3;
    const int bm = ((j & 7) << 3) + xcd;   // 64 m-tiles; same bm -> same XCD
    const int rest = j >> 3;
    const int bn = rest % nbn;
    const int sp = rest / nbn;
    const int e0 = sp * 4;

    f32x4 acc[4][2];
#pragma unroll
    for (int mi = 0; mi < 4; ++mi)
#pragma unroll
        for (int ni = 0; ni < 2; ++ni) acc[mi][ni] = (f32x4){0.f, 0.f, 0.f, 0.f};

    // per-lane blend scalars: blh[e][mi] = blend[e0+e, row(mi,l15)]
    _Float16 blh[4][4];
#pragma unroll
    for (int e = 0; e < 4; ++e)
#pragma unroll
        for (int mi = 0; mi < 4; ++mi)
            blh[e][mi] = (_Float16)blend[(e0 + e) * BATCH + bm * 128 + wm * 64 +
                                         mi * 16 + l15];

    const int l8 = lane & 7, h8 = lane >> 3;
    const int c8 = (l8 ^ h8) << 3;  // XOR-swizzled k source offset
    const u16* gA = A + (size_t)(bm * 128 + w * 8 + h8) * KP + c8;
    const u16* gBu[8];
#pragma unroll
    for (int u = 0; u < 8; ++u) {
        int r = u * 64 + w * 8 + h8;  // row in the 512-row (4-expert) B slab
        gBu[u] = Bw + ((size_t)(e0 + (r >> 7)) * OUTP + bn * 128 + (r & 127)) * KP + c8;
    }
    u16* sA0 = As + w * 512;
    u16* sB0 = Bs + w * 512;

    for (int kt = 0; kt < 8; ++kt) {
        const int ko = kt * 64;
        async16(gA + ko, sA0);
        async16(gA + (size_t)64 * KP + ko, sA0 + 4096);
#pragma unroll
        for (int u = 0; u < 8; ++u) async16(gBu[u] + ko, sB0 + u * 4096);
        __syncthreads();
#pragma unroll
        for (int ks = 0; ks < 2; ++ks) {
            const int cs = (((q ^ (l15 & 7)) << 3) ^ (ks << 5));
            f16x8 af[4];
#pragma unroll
            for (int mi = 0; mi < 4; ++mi)
                af[mi] = *reinterpret_cast<const f16x8*>(
                    &As[(wm * 64 + mi * 16 + l15) * 64 + cs]);
#pragma unroll
            for (int e = 0; e < 4; ++e) {
                f16x8 b0 = *reinterpret_cast<const f16x8*>(
                    &Bs[(e * 128 + wn * 32 + l15) * 64 + cs]);
                f16x8 b1 = *reinterpret_cast<const f16x8*>(
                    &Bs[(e * 128 + wn * 32 + 16 + l15) * 64 + cs]);
#pragma unroll
                for (int mi = 0; mi < 4; ++mi) {
                    f16x8 as = af[mi] * blh[e][mi];
                    acc[mi][0] = __builtin_amdgcn_mfma_f32_16x16x32_f16(
                        as, b0, acc[mi][0], 0, 0, 0);
                    acc[mi][1] = __builtin_amdgcn_mfma_f32_16x16x32_f16(
                        as, b1, acc[mi][1], 0, 0, 0);
                }
            }
        }
        __syncthreads();
    }

    // write fp16 partials (small: 2 splits only)
#pragma unroll
    for (int mi = 0; mi < 4; ++mi) {
#pragma unroll
        for (int ni = 0; ni < 2; ++ni) {
            int gcol = bn * 128 + wn * 32 + ni * 16 + l15;
#pragma unroll
            for (int r = 0; r < 4; ++r) {
                int rl = wm * 64 + mi * 16 + q * 4 + r;
                P[((size_t)sp * BATCH + bm * 128 + rl) * OUTP + gcol] =
                    f2h(acc[mi][ni][r]);
            }
        }
    }
}

// h[b,n] = elu( P0[b,n] + P1[b,n] + sum_e bl[e,b]*bias[e,n] ), fp16 out.
__global__ __launch_bounds__(256) void combine_h(
    const u16* __restrict__ P, const float* __restrict__ blend,
    const float* __restrict__ bias, u16* __restrict__ h) {
    const int w = threadIdx.x >> 6, lane = threadIdx.x & 63;
    const int b = blockIdx.x * 4 + w;
    const int o0 = lane << 3;
    float bl[E_EXP];
#pragma unroll
    for (int e = 0; e < E_EXP; ++e) bl[e] = blend[e * BATCH + b];
    const f16x8 p0 = *reinterpret_cast<const f16x8*>(P + (size_t)b * 512 + o0);
    const f16x8 p1 = *reinterpret_cast<const f16x8*>(
        P + ((size_t)BATCH + b) * 512 + o0);
    float v[8];
#pragma unroll
    for (int jj = 0; jj < 8; ++jj) v[jj] = (float)p0[jj] + (float)p1[jj];
#pragma unroll
    for (int e = 0; e < E_EXP; ++e) {
        const float* bp = bias + e * 512 + o0;
        float4 a = *reinterpret_cast<const float4*>(bp);
        float4 c = *reinterpret_cast<const float4*>(bp + 4);
        float s = bl[e];
        v[0] += s * a.x; v[1] += s * a.y; v[2] += s * a.z; v[3] += s * a.w;
        v[4] += s * c.x; v[5] += s * c.y; v[6] += s * c.z; v[7] += s * c.w;
    }
    u16x8 o;
#pragma unroll
    for (int jj = 0; jj < 8; ++jj) {
        float t = v[jj] > 0.f ? v[jj] : expm1f(v[jj]);
        o[jj] = f2h(t);
    }
    *reinterpret_cast<u16x8*>(h + (size_t)b * 512 + o0) = o;
}

// logits = P0+P1 + blended bias; softmax over 363 -> fp32 out.
__global__ __launch_bounds__(128) void combine_softmax(
    const u16* __restrict__ P, const float* __restrict__ blend,
    const float* __restrict__ bias, float* __restrict__ out) {
    const int b = blockIdx.x;
    const int tid = threadIdx.x, lane = tid & 63, w = tid >> 6;
    float bl[E_EXP];
#pragma unroll
    for (int e = 0; e < E_EXP; ++e) bl[e] = blend[e * BATCH + b];
    float v[3];
    int n = 0;
    float mx = -3.4e38f;
    for (int i = tid; i < D3; i += 128) {
        float s = (float)*reinterpret_cast<const _Float16*>(
                      P + (size_t)b * N3PAD + i) +
                  (float)*reinterpret_cast<const _Float16*>(
                      P + ((size_t)BATCH + b) * N3PAD + i);
#pragma unroll
        for (int e = 0; e < E_EXP; ++e) s += bl[e] * bias[e * D3 + i];
        v[n] = s; mx = fmaxf(mx, s); ++n;
    }
#pragma unroll
    for (int off = 32; off >= 1; off >>= 1) mx = fmaxf(mx, __shfl_xor(mx, off, 64));
    __shared__ float sm[4];
    if (lane == 0) sm[w] = mx;
    __syncthreads();
    mx = fmaxf(sm[0], sm[1]);
    float s = 0.f;
    for (int jj = 0; jj < n; ++jj) { v[jj] = expf(v[jj] - mx); s += v[jj]; }
#pragma unroll
    for (int off = 32; off >= 1; off >>= 1) s += __shfl_xor(s, off, 64);
    if (lane == 0) sm[2 + w] = s;
    __syncthreads();
    float inv = 1.f / (sm[2] + sm[3]);
    n = 0;
    for (int i = tid; i < D3; i += 128) { out[(size_t)b * D3 + i] = v[n] * inv; ++n; }
}

extern "C" void kernel_launch(void* const* d_in, const int* in_sizes, int n_in,
                              void* d_out, int out_size, void* d_ws, size_t ws_size,
                              hipStream_t stream) {
    const float* x = (const float*)d_in[0];
    const float* blend = (const float*)d_in[1];
    const float* W1 = (const float*)d_in[2];
    const float* b1 = (const float*)d_in[3];
    const float* W2 = (const float*)d_in[4];
    const float* b2 = (const float*)d_in[5];
    const float* W3 = (const float*)d_in[6];
    const float* b3 = (const float*)d_in[7];
    float* outp = (float*)d_out;

    char* ws = (char*)d_ws;
    u16* wf1 = (u16*)ws; ws += (size_t)E_EXP * 512 * KP * 2;    // 4.19 MB
    u16* wf2 = (u16*)ws; ws += (size_t)E_EXP * 512 * KP * 2;    // 4.19 MB
    u16* wf3 = (u16*)ws; ws += (size_t)E_EXP * N3PAD * KP * 2;  // 3.15 MB
    u16* xp = (u16*)ws;  ws += (size_t)BATCH * KP * 2;          // 8.39 MB
    u16* h1 = (u16*)ws;  ws += (size_t)BATCH * KP * 2;          // 8.39 MB
    u16* h2 = (u16*)ws;  ws += (size_t)BATCH * KP * 2;          // 8.39 MB
    u16* P = (u16*)ws;                                          // 2*8192*512*2 = 16.8 MB

    pack_all<<<1024, 256, 0, stream>>>(W1, W2, W3, wf1, wf2, wf3);
    pad_x<<<2048, 256, 0, stream>>>(x, xp);

    gemm_fused<<<64 * 4 * 2, 512, 0, stream>>>(xp, wf1, blend, P, 512, 4);
    combine_h<<<BATCH / 4, 256, 0, stream>>>(P, blend, b1, h1);
    gemm_fused<<<64 * 4 * 2, 512, 0, stream>>>(h1, wf2, blend, P, 512, 4);
    combine_h<<<BATCH / 4, 256, 0, stream>>>(P, blend, b2, h2);
    gemm_fused<<<64 * 3 * 2, 512, 0, stream>>>(h2, wf3, blend, P, N3PAD, 3);
    combine_softmax<<<BATCH, 128, 0, stream>>>(P, blend, b3, outp);
}

// Round 7
// 396.216 us; speedup vs baseline: 1.8708x; 1.8708x over previous
//
#include <hip/hip_runtime.h>
#include <cstdint>

#define E_EXP 8
#define BATCH 8192
#define D0 480
#define D1 512
#define D2 512
#define D3 363
#define KP 512      // padded per-expert K
#define N3PAD 384

typedef _Float16 f16x8 __attribute__((ext_vector_type(8)));
typedef float f32x4 __attribute__((ext_vector_type(4)));
typedef unsigned short u16;
typedef u16 u16x8 __attribute__((ext_vector_type(8)));

__device__ __forceinline__ u16 f2h(float f) {
    _Float16 h = (_Float16)f;
    return __builtin_bit_cast(u16, h);
}

// async global->LDS, 16B per lane; LDS dest = wave-uniform base + lane*16
__device__ __forceinline__ void async16(const u16* g, u16* s) {
    __builtin_amdgcn_global_load_lds(
        reinterpret_cast<const __attribute__((address_space(1))) void*>(
            reinterpret_cast<uintptr_t>(g)),
        reinterpret_cast<__attribute__((address_space(3))) void*>(
            reinterpret_cast<uintptr_t>(s)),
        16, 0, 0);
}

// W[e][o][i] fp32 -> wf[e][o][0..511] fp16, zero-padded in o (to OUTP) and i (to 512)
__device__ __forceinline__ void pack_seg(const float* __restrict__ src,
                                         u16* __restrict__ dst,
                                         int OUT_src, int OUTP, int IN_src) {
    int total = E_EXP * OUTP * 128;
    int in4 = IN_src >> 2;
    for (int idx = blockIdx.x * blockDim.x + threadIdx.x; idx < total;
         idx += gridDim.x * blockDim.x) {
        int e = idx / (OUTP * 128);
        int r = idx - e * OUTP * 128;
        int o = r >> 7;
        int k4 = r & 127;
        ushort4 w;
        if (o < OUT_src && k4 < in4) {
            const float4 v = *reinterpret_cast<const float4*>(
                src + ((size_t)e * OUT_src + o) * IN_src + (k4 << 2));
            w.x = f2h(v.x); w.y = f2h(v.y); w.z = f2h(v.z); w.w = f2h(v.w);
        } else {
            w.x = 0; w.y = 0; w.z = 0; w.w = 0;
        }
        *reinterpret_cast<ushort4*>(dst + ((size_t)e * OUTP + o) * KP + (k4 << 2)) = w;
    }
}

__global__ void pack_all(const float* __restrict__ W1, const float* __restrict__ W2,
                         const float* __restrict__ W3, u16* __restrict__ wf1,
                         u16* __restrict__ wf2, u16* __restrict__ wf3) {
    pack_seg(W1, wf1, 512, 512, D0);
    pack_seg(W2, wf2, 512, 512, D1);
    pack_seg(W3, wf3, D3, N3PAD, D2);
}

// x (8192x480 fp32) -> xp (8192x512 fp16, zero-padded)
__global__ void pad_x(const float* __restrict__ x, u16* __restrict__ xp) {
    int total = BATCH * 128;
    for (int idx = blockIdx.x * blockDim.x + threadIdx.x; idx < total;
         idx += gridDim.x * blockDim.x) {
        int b = idx >> 7, k4 = idx & 127;
        ushort4 w;
        if (k4 < 120) {
            const float4 v = *reinterpret_cast<const float4*>(
                x + (size_t)b * D0 + (k4 << 2));
            w.x = f2h(v.x); w.y = f2h(v.y); w.z = f2h(v.z); w.w = f2h(v.w);
        } else {
            w.x = 0; w.y = 0; w.z = 0; w.w = 0;
        }
        *reinterpret_cast<ushort4*>(xp + (size_t)b * KP + (k4 << 2)) = w;
    }
}

// Blended GEMM, R4 skeleton + in-register blend on the A-fragment.
// P[sp][m][n] = sum_{e in split sp} bl[e,m] * (A @ W_e^T)[m,n]
// Tile 128x128, BK=64; 512 thr = 8 waves (2m x 4n); 32 barrier-passes
// (4 experts x 8 k-tiles); A re-read per expert hits L2 (A slab is 8.4 MB).
__global__ __launch_bounds__(512, 8) void gemm_blend(
    const u16* __restrict__ A, const u16* __restrict__ Bw,
    const float* __restrict__ blend, u16* __restrict__ P, int OUTP, int nbn) {
    __shared__ __align__(16) u16 As[8192];
    __shared__ __align__(16) u16 Bs[8192];
    const int tid = threadIdx.x;
    const int w = tid >> 6, lane = tid & 63;
    const int wm = w & 1, wn = w >> 1;
    const int q = lane >> 4, l15 = lane & 15;

    const int id = blockIdx.x;
    const int xcd = id & 7;
    const int j = id >> 3;
    const int bm = ((j & 7) << 3) + xcd;   // 64 m-tiles; same bm -> same XCD
    const int rest = j >> 3;
    const int bn = rest % nbn;
    const int sp = rest / nbn;

    f32x4 acc[4][2];
#pragma unroll
    for (int mi = 0; mi < 4; ++mi)
#pragma unroll
        for (int ni = 0; ni < 2; ++ni) acc[mi][ni] = (f32x4){0.f, 0.f, 0.f, 0.f};

    const int l8 = lane & 7, h8 = lane >> 3;
    const int c8 = (l8 ^ h8) << 3;  // XOR-swizzled k source offset
    const u16* gA = A + (size_t)(bm * 128 + w * 8 + h8) * KP + c8;
    u16* sA0 = As + w * 512;
    u16* sB0 = Bs + w * 512;

    for (int ei = 0; ei < 4; ++ei) {
        const int e = sp * 4 + ei;
        // per-lane blend scalars for this expert: row m = bm*128+wm*64+mi*16+l15
        _Float16 blh[4];
#pragma unroll
        for (int mi = 0; mi < 4; ++mi)
            blh[mi] = (_Float16)blend[e * BATCH + bm * 128 + wm * 64 + mi * 16 + l15];
        const u16* gB = Bw + ((size_t)e * OUTP + bn * 128 + w * 8 + h8) * KP + c8;
#pragma unroll
        for (int ek = 0; ek < 8; ++ek) {
            const int ko = ek * 64;
            async16(gA + ko, sA0);
            async16(gA + (size_t)64 * KP + ko, sA0 + 4096);
            async16(gB + ko, sB0);
            async16(gB + (size_t)64 * KP + ko, sB0 + 4096);
            __syncthreads();
#pragma unroll
            for (int ks = 0; ks < 2; ++ks) {
                const int cs = (((q ^ (l15 & 7)) << 3) ^ (ks << 5));
                f16x8 bf0 = *reinterpret_cast<const f16x8*>(
                    &Bs[(wn * 32 + l15) * 64 + cs]);
                f16x8 bf1 = *reinterpret_cast<const f16x8*>(
                    &Bs[(wn * 32 + 16 + l15) * 64 + cs]);
#pragma unroll
                for (int mi = 0; mi < 4; ++mi) {
                    f16x8 af = *reinterpret_cast<const f16x8*>(
                        &As[(wm * 64 + mi * 16 + l15) * 64 + cs]);
                    f16x8 as = af * blh[mi];
                    acc[mi][0] = __builtin_amdgcn_mfma_f32_16x16x32_f16(
                        as, bf0, acc[mi][0], 0, 0, 0);
                    acc[mi][1] = __builtin_amdgcn_mfma_f32_16x16x32_f16(
                        as, bf1, acc[mi][1], 0, 0, 0);
                }
            }
            __syncthreads();
        }
    }

    // write fp16 partials
#pragma unroll
    for (int mi = 0; mi < 4; ++mi) {
#pragma unroll
        for (int ni = 0; ni < 2; ++ni) {
            int gcol = bn * 128 + wn * 32 + ni * 16 + l15;
#pragma unroll
            for (int r = 0; r < 4; ++r) {
                int rl = wm * 64 + mi * 16 + q * 4 + r;
                P[((size_t)sp * BATCH + bm * 128 + rl) * OUTP + gcol] =
                    f2h(acc[mi][ni][r]);
            }
        }
    }
}

// h[b,n] = elu( P0[b,n] + P1[b,n] + sum_e bl[e,b]*bias[e,n] ), fp16 out.
__global__ __launch_bounds__(256) void combine_h(
    const u16* __restrict__ P, const float* __restrict__ blend,
    const float* __restrict__ bias, u16* __restrict__ h) {
    const int w = threadIdx.x >> 6, lane = threadIdx.x & 63;
    const int b = blockIdx.x * 4 + w;
    const int o0 = lane << 3;
    float bl[E_EXP];
#pragma unroll
    for (int e = 0; e < E_EXP; ++e) bl[e] = blend[e * BATCH + b];
    const f16x8 p0 = *reinterpret_cast<const f16x8*>(P + (size_t)b * 512 + o0);
    const f16x8 p1 = *reinterpret_cast<const f16x8*>(
        P + ((size_t)BATCH + b) * 512 + o0);
    float v[8];
#pragma unroll
    for (int jj = 0; jj < 8; ++jj) v[jj] = (float)p0[jj] + (float)p1[jj];
#pragma unroll
    for (int e = 0; e < E_EXP; ++e) {
        const float* bp = bias + e * 512 + o0;
        float4 a = *reinterpret_cast<const float4*>(bp);
        float4 c = *reinterpret_cast<const float4*>(bp + 4);
        float s = bl[e];
        v[0] += s * a.x; v[1] += s * a.y; v[2] += s * a.z; v[3] += s * a.w;
        v[4] += s * c.x; v[5] += s * c.y; v[6] += s * c.z; v[7] += s * c.w;
    }
    u16x8 o;
#pragma unroll
    for (int jj = 0; jj < 8; ++jj) {
        float t = v[jj] > 0.f ? v[jj] : expm1f(v[jj]);
        o[jj] = f2h(t);
    }
    *reinterpret_cast<u16x8*>(h + (size_t)b * 512 + o0) = o;
}

// logits = P0+P1 + blended bias; softmax over 363 -> fp32 out.
__global__ __launch_bounds__(128) void combine_softmax(
    const u16* __restrict__ P, const float* __restrict__ blend,
    const float* __restrict__ bias, float* __restrict__ out) {
    const int b = blockIdx.x;
    const int tid = threadIdx.x, lane = tid & 63, w = tid >> 6;
    float bl[E_EXP];
#pragma unroll
    for (int e = 0; e < E_EXP; ++e) bl[e] = blend[e * BATCH + b];
    float v[3];
    int n = 0;
    float mx = -3.4e38f;
    for (int i = tid; i < D3; i += 128) {
        float s = (float)*reinterpret_cast<const _Float16*>(
                      P + (size_t)b * N3PAD + i) +
                  (float)*reinterpret_cast<const _Float16*>(
                      P + ((size_t)BATCH + b) * N3PAD + i);
#pragma unroll
        for (int e = 0; e < E_EXP; ++e) s += bl[e] * bias[e * D3 + i];
        v[n] = s; mx = fmaxf(mx, s); ++n;
    }
#pragma unroll
    for (int off = 32; off >= 1; off >>= 1) mx = fmaxf(mx, __shfl_xor(mx, off, 64));
    __shared__ float sm[4];
    if (lane == 0) sm[w] = mx;
    __syncthreads();
    mx = fmaxf(sm[0], sm[1]);
    float s = 0.f;
    for (int jj = 0; jj < n; ++jj) { v[jj] = expf(v[jj] - mx); s += v[jj]; }
#pragma unroll
    for (int off = 32; off >= 1; off >>= 1) s += __shfl_xor(s, off, 64);
    if (lane == 0) sm[2 + w] = s;
    __syncthreads();
    float inv = 1.f / (sm[2] + sm[3]);
    n = 0;
    for (int i = tid; i < D3; i += 128) { out[(size_t)b * D3 + i] = v[n] * inv; ++n; }
}

extern "C" void kernel_launch(void* const* d_in, const int* in_sizes, int n_in,
                              void* d_out, int out_size, void* d_ws, size_t ws_size,
                              hipStream_t stream) {
    const float* x = (const float*)d_in[0];
    const float* blend = (const float*)d_in[1];
    const float* W1 = (const float*)d_in[2];
    const float* b1 = (const float*)d_in[3];
    const float* W2 = (const float*)d_in[4];
    const float* b2 = (const float*)d_in[5];
    const float* W3 = (const float*)d_in[6];
    const float* b3 = (const float*)d_in[7];
    float* outp = (float*)d_out;

    char* ws = (char*)d_ws;
    u16* wf1 = (u16*)ws; ws += (size_t)E_EXP * 512 * KP * 2;    // 4.19 MB
    u16* wf2 = (u16*)ws; ws += (size_t)E_EXP * 512 * KP * 2;    // 4.19 MB
    u16* wf3 = (u16*)ws; ws += (size_t)E_EXP * N3PAD * KP * 2;  // 3.15 MB
    u16* xp = (u16*)ws;  ws += (size_t)BATCH * KP * 2;          // 8.39 MB
    u16* h1 = (u16*)ws;  ws += (size_t)BATCH * KP * 2;          // 8.39 MB
    u16* h2 = (u16*)ws;  ws += (size_t)BATCH * KP * 2;          // 8.39 MB
    u16* P = (u16*)ws;                                          // 2*8192*512*2 = 16.8 MB

    pack_all<<<1024, 256, 0, stream>>>(W1, W2, W3, wf1, wf2, wf3);
    pad_x<<<2048, 256, 0, stream>>>(x, xp);

    gemm_blend<<<64 * 4 * 2, 512, 0, stream>>>(xp, wf1, blend, P, 512, 4);
    combine_h<<<BATCH / 4, 256, 0, stream>>>(P, blend, b1, h1);
    gemm_blend<<<64 * 4 * 2, 512, 0, stream>>>(h1, wf2, blend, P, 512, 4);
    combine_h<<<BATCH / 4, 256, 0, stream>>>(P, blend, b2, h2);
    gemm_blend<<<64 * 3 * 2, 512, 0, stream>>>(h2, wf3, blend, P, N3PAD, 3);
    combine_softmax<<<BATCH, 128, 0, stream>>>(P, blend, b3, outp);
}

// Round 8
// 393.727 us; speedup vs baseline: 1.8826x; 1.0063x over previous
//
#include <hip/hip_runtime.h>
#include <cstdint>

#define E_EXP 8
#define BATCH 8192
#define D0 480
#define D1 512
#define D2 512
#define D3 363
#define KP 512      // padded per-expert K
#define N3PAD 384

typedef _Float16 f16x8 __attribute__((ext_vector_type(8)));
typedef float f32x4 __attribute__((ext_vector_type(4)));
typedef unsigned short u16;
typedef u16 u16x8 __attribute__((ext_vector_type(8)));

__device__ __forceinline__ u16 f2h(float f) {
    _Float16 h = (_Float16)f;
    return __builtin_bit_cast(u16, h);
}

// async global->LDS, 16B per lane; LDS dest = wave-uniform base + lane*16
__device__ __forceinline__ void async16(const u16* g, u16* s) {
    __builtin_amdgcn_global_load_lds(
        reinterpret_cast<const __attribute__((address_space(1))) void*>(
            reinterpret_cast<uintptr_t>(g)),
        reinterpret_cast<__attribute__((address_space(3))) void*>(
            reinterpret_cast<uintptr_t>(s)),
        16, 0, 0);
}

// W[e][o][i] fp32 -> wf[e][o][0..511] fp16, zero-padded in o (to OUTP) and i (to 512)
__device__ __forceinline__ void pack_seg(const float* __restrict__ src,
                                         u16* __restrict__ dst,
                                         int OUT_src, int OUTP, int IN_src) {
    int total = E_EXP * OUTP * 128;
    int in4 = IN_src >> 2;
    for (int idx = blockIdx.x * blockDim.x + threadIdx.x; idx < total;
         idx += gridDim.x * blockDim.x) {
        int e = idx / (OUTP * 128);
        int r = idx - e * OUTP * 128;
        int o = r >> 7;
        int k4 = r & 127;
        ushort4 w;
        if (o < OUT_src && k4 < in4) {
            const float4 v = *reinterpret_cast<const float4*>(
                src + ((size_t)e * OUT_src + o) * IN_src + (k4 << 2));
            w.x = f2h(v.x); w.y = f2h(v.y); w.z = f2h(v.z); w.w = f2h(v.w);
        } else {
            w.x = 0; w.y = 0; w.z = 0; w.w = 0;
        }
        *reinterpret_cast<ushort4*>(dst + ((size_t)e * OUTP + o) * KP + (k4 << 2)) = w;
    }
}

__global__ void pack_all(const float* __restrict__ W1, const float* __restrict__ W2,
                         const float* __restrict__ W3, u16* __restrict__ wf1,
                         u16* __restrict__ wf2, u16* __restrict__ wf3) {
    pack_seg(W1, wf1, 512, 512, D0);
    pack_seg(W2, wf2, 512, 512, D1);
    pack_seg(W3, wf3, D3, N3PAD, D2);
}

// x (8192x480 fp32) -> xp (8192x512 fp16, zero-padded)
__global__ void pad_x(const float* __restrict__ x, u16* __restrict__ xp) {
    int total = BATCH * 128;
    for (int idx = blockIdx.x * blockDim.x + threadIdx.x; idx < total;
         idx += gridDim.x * blockDim.x) {
        int b = idx >> 7, k4 = idx & 127;
        ushort4 w;
        if (k4 < 120) {
            const float4 v = *reinterpret_cast<const float4*>(
                x + (size_t)b * D0 + (k4 << 2));
            w.x = f2h(v.x); w.y = f2h(v.y); w.z = f2h(v.z); w.w = f2h(v.w);
        } else {
            w.x = 0; w.y = 0; w.z = 0; w.w = 0;
        }
        *reinterpret_cast<ushort4*>(xp + (size_t)b * KP + (k4 << 2)) = w;
    }
}

// Blended GEMM, expert loop inside k loop, A staged once per k-tile,
// A/B double-buffered so next-step loads fly during current MFMA block.
// P[sp][m][n] = sum_{e in split sp} bl[e,m] * (A @ W_e^T)[m,n]
// Tile 128x128, BK=64; 512 thr = 8 waves (2m x 4n).
// XCD key = (bm&3) | (sp<<2): per-XCD set = A 2MB + sp-half weights 2.1MB ~ L2.
__global__ __launch_bounds__(512, 4) void gemm_blend(
    const u16* __restrict__ A, const u16* __restrict__ Bw,
    const float* __restrict__ blend, u16* __restrict__ P, int OUTP, int nbn) {
    __shared__ __align__(16) u16 As[2][8192];
    __shared__ __align__(16) u16 Bs[2][8192];
    const int tid = threadIdx.x;
    const int w = tid >> 6, lane = tid & 63;
    const int wm = w & 1, wn = w >> 1;
    const int q = lane >> 4, l15 = lane & 15;

    const int id = blockIdx.x;
    const int xcd = id & 7;
    const int sp = xcd >> 2;
    const int bmg = xcd & 3;
    const int j = id >> 3;
    const int bm = (j & 15) * 4 + bmg;   // 64 m-tiles; bm%4 pinned to XCD group
    const int bn = j >> 4;               // 0..nbn-1

    f32x4 acc[4][2];
#pragma unroll
    for (int mi = 0; mi < 4; ++mi)
#pragma unroll
        for (int ni = 0; ni < 2; ++ni) acc[mi][ni] = (f32x4){0.f, 0.f, 0.f, 0.f};

    // per-lane blend scalars: blh[ei][mi] for experts sp*4+ei, row = ...+mi*16+l15
    _Float16 blh[4][4];
#pragma unroll
    for (int e = 0; e < 4; ++e)
#pragma unroll
        for (int mi = 0; mi < 4; ++mi)
            blh[e][mi] = (_Float16)blend[(sp * 4 + e) * BATCH + bm * 128 + wm * 64 +
                                         mi * 16 + l15];

    const int l8 = lane & 7, h8 = lane >> 3;
    const int c8 = (l8 ^ h8) << 3;  // XOR-swizzled k source offset
    const u16* gA = A + (size_t)(bm * 128 + w * 8 + h8) * KP + c8;
    const size_t EST = (size_t)OUTP * KP;         // expert stride (elems)
    const u16* gB = Bw + (size_t)(sp * 4) * EST +
                    (size_t)(bn * 128 + w * 8 + h8) * KP + c8;
    const size_t rstep = (size_t)64 * KP;
    const int wo = w * 512;

    // stage step 0: A(k0), B(e0,k0)
    async16(gA, &As[0][wo]);
    async16(gA + rstep, &As[0][wo + 4096]);
    async16(gB, &Bs[0][wo]);
    async16(gB + rstep, &Bs[0][wo + 4096]);
    __syncthreads();

    for (int ek = 0; ek < 8; ++ek) {
        const int ab = ek & 1;
#pragma unroll
        for (int ei = 0; ei < 4; ++ei) {
            const int bb = ei & 1;
            // issue next-step loads into the other buffers
            if (ei < 3) {
                gB += EST;
                async16(gB, &Bs[bb ^ 1][wo]);
                async16(gB + rstep, &Bs[bb ^ 1][wo + 4096]);
            } else if (ek < 7) {
                gB = gB + 64 - (ptrdiff_t)(3 * EST);
                gA += 64;
                async16(gA, &As[ab ^ 1][wo]);
                async16(gA + rstep, &As[ab ^ 1][wo + 4096]);
                async16(gB, &Bs[bb ^ 1][wo]);
                async16(gB + rstep, &Bs[bb ^ 1][wo + 4096]);
            }
            // MFMA on current buffers
#pragma unroll
            for (int ks = 0; ks < 2; ++ks) {
                const int cs = (((q ^ (l15 & 7)) << 3) ^ (ks << 5));
                f16x8 bf0 = *reinterpret_cast<const f16x8*>(
                    &Bs[bb][(wn * 32 + l15) * 64 + cs]);
                f16x8 bf1 = *reinterpret_cast<const f16x8*>(
                    &Bs[bb][(wn * 32 + 16 + l15) * 64 + cs]);
#pragma unroll
                for (int mi = 0; mi < 4; ++mi) {
                    f16x8 af = *reinterpret_cast<const f16x8*>(
                        &As[ab][(wm * 64 + mi * 16 + l15) * 64 + cs]);
                    f16x8 as = af * blh[ei][mi];
                    acc[mi][0] = __builtin_amdgcn_mfma_f32_16x16x32_f16(
                        as, bf0, acc[mi][0], 0, 0, 0);
                    acc[mi][1] = __builtin_amdgcn_mfma_f32_16x16x32_f16(
                        as, bf1, acc[mi][1], 0, 0, 0);
                }
            }
            __syncthreads();
        }
    }

    // write fp16 partials
#pragma unroll
    for (int mi = 0; mi < 4; ++mi) {
#pragma unroll
        for (int ni = 0; ni < 2; ++ni) {
            int gcol = bn * 128 + wn * 32 + ni * 16 + l15;
#pragma unroll
            for (int r = 0; r < 4; ++r) {
                int rl = wm * 64 + mi * 16 + q * 4 + r;
                P[((size_t)sp * BATCH + bm * 128 + rl) * OUTP + gcol] =
                    f2h(acc[mi][ni][r]);
            }
        }
    }
}

// h[b,n] = elu( P0[b,n] + P1[b,n] + sum_e bl[e,b]*bias[e,n] ), fp16 out.
__global__ __launch_bounds__(256) void combine_h(
    const u16* __restrict__ P, const float* __restrict__ blend,
    const float* __restrict__ bias, u16* __restrict__ h) {
    const int w = threadIdx.x >> 6, lane = threadIdx.x & 63;
    const int b = blockIdx.x * 4 + w;
    const int o0 = lane << 3;
    float bl[E_EXP];
#pragma unroll
    for (int e = 0; e < E_EXP; ++e) bl[e] = blend[e * BATCH + b];
    const f16x8 p0 = *reinterpret_cast<const f16x8*>(P + (size_t)b * 512 + o0);
    const f16x8 p1 = *reinterpret_cast<const f16x8*>(
        P + ((size_t)BATCH + b) * 512 + o0);
    float v[8];
#pragma unroll
    for (int jj = 0; jj < 8; ++jj) v[jj] = (float)p0[jj] + (float)p1[jj];
#pragma unroll
    for (int e = 0; e < E_EXP; ++e) {
        const float* bp = bias + e * 512 + o0;
        float4 a = *reinterpret_cast<const float4*>(bp);
        float4 c = *reinterpret_cast<const float4*>(bp + 4);
        float s = bl[e];
        v[0] += s * a.x; v[1] += s * a.y; v[2] += s * a.z; v[3] += s * a.w;
        v[4] += s * c.x; v[5] += s * c.y; v[6] += s * c.z; v[7] += s * c.w;
    }
    u16x8 o;
#pragma unroll
    for (int jj = 0; jj < 8; ++jj) {
        float t = v[jj] > 0.f ? v[jj] : expm1f(v[jj]);
        o[jj] = f2h(t);
    }
    *reinterpret_cast<u16x8*>(h + (size_t)b * 512 + o0) = o;
}

// logits = P0+P1 + blended bias; softmax over 363 -> fp32 out.
__global__ __launch_bounds__(128) void combine_softmax(
    const u16* __restrict__ P, const float* __restrict__ blend,
    const float* __restrict__ bias, float* __restrict__ out) {
    const int b = blockIdx.x;
    const int tid = threadIdx.x, lane = tid & 63, w = tid >> 6;
    float bl[E_EXP];
#pragma unroll
    for (int e = 0; e < E_EXP; ++e) bl[e] = blend[e * BATCH + b];
    float v[3];
    int n = 0;
    float mx = -3.4e38f;
    for (int i = tid; i < D3; i += 128) {
        float s = (float)*reinterpret_cast<const _Float16*>(
                      P + (size_t)b * N3PAD + i) +
                  (float)*reinterpret_cast<const _Float16*>(
                      P + ((size_t)BATCH + b) * N3PAD + i);
#pragma unroll
        for (int e = 0; e < E_EXP; ++e) s += bl[e] * bias[e * D3 + i];
        v[n] = s; mx = fmaxf(mx, s); ++n;
    }
#pragma unroll
    for (int off = 32; off >= 1; off >>= 1) mx = fmaxf(mx, __shfl_xor(mx, off, 64));
    __shared__ float sm[4];
    if (lane == 0) sm[w] = mx;
    __syncthreads();
    mx = fmaxf(sm[0], sm[1]);
    float s = 0.f;
    for (int jj = 0; jj < n; ++jj) { v[jj] = expf(v[jj] - mx); s += v[jj]; }
#pragma unroll
    for (int off = 32; off >= 1; off >>= 1) s += __shfl_xor(s, off, 64);
    if (lane == 0) sm[2 + w] = s;
    __syncthreads();
    float inv = 1.f / (sm[2] + sm[3]);
    n = 0;
    for (int i = tid; i < D3; i += 128) { out[(size_t)b * D3 + i] = v[n] * inv; ++n; }
}

extern "C" void kernel_launch(void* const* d_in, const int* in_sizes, int n_in,
                              void* d_out, int out_size, void* d_ws, size_t ws_size,
                              hipStream_t stream) {
    const float* x = (const float*)d_in[0];
    const float* blend = (const float*)d_in[1];
    const float* W1 = (const float*)d_in[2];
    const float* b1 = (const float*)d_in[3];
    const float* W2 = (const float*)d_in[4];
    const float* b2 = (const float*)d_in[5];
    const float* W3 = (const float*)d_in[6];
    const float* b3 = (const float*)d_in[7];
    float* outp = (float*)d_out;

    char* ws = (char*)d_ws;
    u16* wf1 = (u16*)ws; ws += (size_t)E_EXP * 512 * KP * 2;    // 4.19 MB
    u16* wf2 = (u16*)ws; ws += (size_t)E_EXP * 512 * KP * 2;    // 4.19 MB
    u16* wf3 = (u16*)ws; ws += (size_t)E_EXP * N3PAD * KP * 2;  // 3.15 MB
    u16* xp = (u16*)ws;  ws += (size_t)BATCH * KP * 2;          // 8.39 MB
    u16* h1 = (u16*)ws;  ws += (size_t)BATCH * KP * 2;          // 8.39 MB
    u16* h2 = (u16*)ws;  ws += (size_t)BATCH * KP * 2;          // 8.39 MB
    u16* P = (u16*)ws;                                          // 2*8192*512*2 = 16.8 MB

    pack_all<<<1024, 256, 0, stream>>>(W1, W2, W3, wf1, wf2, wf3);
    pad_x<<<2048, 256, 0, stream>>>(x, xp);

    gemm_blend<<<64 * 4 * 2, 512, 0, stream>>>(xp, wf1, blend, P, 512, 4);
    combine_h<<<BATCH / 4, 256, 0, stream>>>(P, blend, b1, h1);
    gemm_blend<<<64 * 4 * 2, 512, 0, stream>>>(h1, wf2, blend, P, 512, 4);
    combine_h<<<BATCH / 4, 256, 0, stream>>>(P, blend, b2, h2);
    gemm_blend<<<64 * 3 * 2, 512, 0, stream>>>(h2, wf3, blend, P, N3PAD, 3);
    combine_softmax<<<BATCH, 128, 0, stream>>>(P, blend, b3, outp);
}

// Round 9
// 221.247 us; speedup vs baseline: 3.3503x; 1.7796x over previous
//
#include <hip/hip_runtime.h>
#include <cstdint>

#define E_EXP 8
#define BATCH 8192
#define D0 480
#define D1 512
#define D2 512
#define D3 363
#define KP 512      // padded per-expert K
#define N3PAD 384

typedef _Float16 f16x8 __attribute__((ext_vector_type(8)));
typedef float f32x4 __attribute__((ext_vector_type(4)));
typedef unsigned short u16;
typedef u16 u16x8 __attribute__((ext_vector_type(8)));

__device__ __forceinline__ u16 f2h(float f) {
    _Float16 h = (_Float16)f;
    return __builtin_bit_cast(u16, h);
}

// async global->LDS, 16B per lane; LDS dest = wave-uniform base + lane*16
__device__ __forceinline__ void async16(const u16* g, u16* s) {
    __builtin_amdgcn_global_load_lds(
        reinterpret_cast<const __attribute__((address_space(1))) void*>(
            reinterpret_cast<uintptr_t>(g)),
        reinterpret_cast<__attribute__((address_space(3))) void*>(
            reinterpret_cast<uintptr_t>(s)),
        16, 0, 0);
}

// W[e][o][i] fp32 -> wf[e][o][0..511] fp16, zero-padded in o (to OUTP) and i (to 512)
__device__ __forceinline__ void pack_seg(const float* __restrict__ src,
                                         u16* __restrict__ dst,
                                         int OUT_src, int OUTP, int IN_src) {
    int total = E_EXP * OUTP * 128;
    int in4 = IN_src >> 2;
    for (int idx = blockIdx.x * blockDim.x + threadIdx.x; idx < total;
         idx += gridDim.x * blockDim.x) {
        int e = idx / (OUTP * 128);
        int r = idx - e * OUTP * 128;
        int o = r >> 7;
        int k4 = r & 127;
        ushort4 w;
        if (o < OUT_src && k4 < in4) {
            const float4 v = *reinterpret_cast<const float4*>(
                src + ((size_t)e * OUT_src + o) * IN_src + (k4 << 2));
            w.x = f2h(v.x); w.y = f2h(v.y); w.z = f2h(v.z); w.w = f2h(v.w);
        } else {
            w.x = 0; w.y = 0; w.z = 0; w.w = 0;
        }
        *reinterpret_cast<ushort4*>(dst + ((size_t)e * OUTP + o) * KP + (k4 << 2)) = w;
    }
}

__global__ void pack_all(const float* __restrict__ W1, const float* __restrict__ W2,
                         const float* __restrict__ W3, u16* __restrict__ wf1,
                         u16* __restrict__ wf2, u16* __restrict__ wf3) {
    pack_seg(W1, wf1, 512, 512, D0);
    pack_seg(W2, wf2, 512, 512, D1);
    pack_seg(W3, wf3, D3, N3PAD, D2);
}

// x (8192x480 fp32) -> xp (8192x512 fp16, zero-padded)
__global__ void pad_x(const float* __restrict__ x, u16* __restrict__ xp) {
    int total = BATCH * 128;
    for (int idx = blockIdx.x * blockDim.x + threadIdx.x; idx < total;
         idx += gridDim.x * blockDim.x) {
        int b = idx >> 7, k4 = idx & 127;
        ushort4 w;
        if (k4 < 120) {
            const float4 v = *reinterpret_cast<const float4*>(
                x + (size_t)b * D0 + (k4 << 2));
            w.x = f2h(v.x); w.y = f2h(v.y); w.z = f2h(v.z); w.w = f2h(v.w);
        } else {
            w.x = 0; w.y = 0; w.z = 0; w.w = 0;
        }
        *reinterpret_cast<ushort4*>(xp + (size_t)b * KP + (k4 << 2)) = w;
    }
}

// All-expert fused blended GEMM: P[m][n] = sum_e bl[e,m] * (A @ W_e^T)[m,n]
// Tile 256x64, BK=64, only 8 barrier passes; per pass stage A 32KB + all-8-expert
// B slab 64KB; blend applied in-register to A-fragments; acc = final logits.
// 512 thr = 8 waves as 4m x 2n (wave-tile 64m x 32n). Grid 32*nbn, 1 block/CU.
// XCD key on bm: per-XCD set = A-stream 1MB + B k-window ~0.5MB (L2-resident).
__global__ __launch_bounds__(512, 2) void gemm_all(
    const u16* __restrict__ A, const u16* __restrict__ Bw,
    const float* __restrict__ blend, u16* __restrict__ P, int OUTP, int nbn) {
    __shared__ __align__(16) u16 As[16384];  // 32 KB: 256 m-rows x 64 k
    __shared__ __align__(16) u16 Bs[32768];  // 64 KB: 8 e x 64 n x 64 k
    const int tid = threadIdx.x;
    const int w = tid >> 6, lane = tid & 63;
    const int wm2 = w & 3, wn2 = w >> 2;
    const int q = lane >> 4, l15 = lane & 15;

    const int id = blockIdx.x;
    const int xcd = id & 7;
    const int j = id >> 3;
    const int bm = ((j & 3) << 3) + xcd;  // 0..31 (256-row tiles), pinned to XCD
    const int bn = j >> 2;                // 0..nbn-1

    f32x4 acc[4][2];
#pragma unroll
    for (int mi = 0; mi < 4; ++mi)
#pragma unroll
        for (int ni = 0; ni < 2; ++ni) acc[mi][ni] = (f32x4){0.f, 0.f, 0.f, 0.f};

    // per-lane blend scalars: blh[e][mi] = blend[e, bm*256 + wm2*64 + mi*16 + l15]
    _Float16 blh[8][4];
#pragma unroll
    for (int e = 0; e < 8; ++e)
#pragma unroll
        for (int mi = 0; mi < 4; ++mi)
            blh[e][mi] = (_Float16)blend[e * BATCH + bm * 256 + wm2 * 64 +
                                         mi * 16 + l15];

    const int l8 = lane & 7, h8 = lane >> 3;
    const int c8 = (l8 ^ h8) << 3;  // XOR-swizzled k source offset
    const size_t EST = (size_t)OUTP * KP;  // expert stride in Bw
    // wave w stages A rows [w*32, w*32+32) and all 64 n-rows of expert e=w
    const u16* gA = A + (size_t)(bm * 256 + w * 32 + h8) * KP + c8;
    const u16* gB = Bw + (size_t)w * EST + (size_t)(bn * 64 + h8) * KP + c8;
    u16* sA = As + w * 2048;
    u16* sB = Bs + w * 4096;

    for (int kt = 0; kt < 8; ++kt) {
        const int ko = kt * 64;
#pragma unroll
        for (int u = 0; u < 4; ++u)
            async16(gA + (size_t)u * 8 * KP + ko, sA + u * 512);
#pragma unroll
        for (int u = 0; u < 8; ++u)
            async16(gB + (size_t)u * 8 * KP + ko, sB + u * 512);
        __syncthreads();
#pragma unroll
        for (int ks = 0; ks < 2; ++ks) {
            const int cs = (((q ^ (l15 & 7)) << 3) ^ (ks << 5));
            f16x8 af[4];
#pragma unroll
            for (int mi = 0; mi < 4; ++mi)
                af[mi] = *reinterpret_cast<const f16x8*>(
                    &As[(wm2 * 64 + mi * 16 + l15) * 64 + cs]);
#pragma unroll
            for (int e = 0; e < 8; ++e) {
                f16x8 bf0 = *reinterpret_cast<const f16x8*>(
                    &Bs[e * 4096 + (wn2 * 32 + l15) * 64 + cs]);
                f16x8 bf1 = *reinterpret_cast<const f16x8*>(
                    &Bs[e * 4096 + (wn2 * 32 + 16 + l15) * 64 + cs]);
#pragma unroll
                for (int mi = 0; mi < 4; ++mi) {
                    f16x8 as = af[mi] * blh[e][mi];
                    acc[mi][0] = __builtin_amdgcn_mfma_f32_16x16x32_f16(
                        as, bf0, acc[mi][0], 0, 0, 0);
                    acc[mi][1] = __builtin_amdgcn_mfma_f32_16x16x32_f16(
                        as, bf1, acc[mi][1], 0, 0, 0);
                }
            }
        }
        __syncthreads();
    }

    // write fp16 blended logits (pre-bias)
#pragma unroll
    for (int mi = 0; mi < 4; ++mi) {
#pragma unroll
        for (int ni = 0; ni < 2; ++ni) {
            int gcol = bn * 64 + wn2 * 32 + ni * 16 + l15;
#pragma unroll
            for (int r = 0; r < 4; ++r) {
                int rl = wm2 * 64 + mi * 16 + q * 4 + r;
                P[(size_t)(bm * 256 + rl) * OUTP + gcol] = f2h(acc[mi][ni][r]);
            }
        }
    }
}

// h[b,n] = elu( P[b,n] + sum_e bl[e,b]*bias[e,n] ), fp16 out.
__global__ __launch_bounds__(256) void combine_h(
    const u16* __restrict__ P, const float* __restrict__ blend,
    const float* __restrict__ bias, u16* __restrict__ h) {
    const int w = threadIdx.x >> 6, lane = threadIdx.x & 63;
    const int b = blockIdx.x * 4 + w;
    const int o0 = lane << 3;
    float bl[E_EXP];
#pragma unroll
    for (int e = 0; e < E_EXP; ++e) bl[e] = blend[e * BATCH + b];
    const f16x8 p0 = *reinterpret_cast<const f16x8*>(P + (size_t)b * 512 + o0);
    float v[8];
#pragma unroll
    for (int jj = 0; jj < 8; ++jj) v[jj] = (float)p0[jj];
#pragma unroll
    for (int e = 0; e < E_EXP; ++e) {
        const float* bp = bias + e * 512 + o0;
        float4 a = *reinterpret_cast<const float4*>(bp);
        float4 c = *reinterpret_cast<const float4*>(bp + 4);
        float s = bl[e];
        v[0] += s * a.x; v[1] += s * a.y; v[2] += s * a.z; v[3] += s * a.w;
        v[4] += s * c.x; v[5] += s * c.y; v[6] += s * c.z; v[7] += s * c.w;
    }
    u16x8 o;
#pragma unroll
    for (int jj = 0; jj < 8; ++jj) {
        float t = v[jj] > 0.f ? v[jj] : expm1f(v[jj]);
        o[jj] = f2h(t);
    }
    *reinterpret_cast<u16x8*>(h + (size_t)b * 512 + o0) = o;
}

// logits = P + blended bias; softmax over 363 -> fp32 out.
__global__ __launch_bounds__(128) void combine_softmax(
    const u16* __restrict__ P, const float* __restrict__ blend,
    const float* __restrict__ bias, float* __restrict__ out) {
    const int b = blockIdx.x;
    const int tid = threadIdx.x, lane = tid & 63, w = tid >> 6;
    float bl[E_EXP];
#pragma unroll
    for (int e = 0; e < E_EXP; ++e) bl[e] = blend[e * BATCH + b];
    float v[3];
    int n = 0;
    float mx = -3.4e38f;
    for (int i = tid; i < D3; i += 128) {
        float s = (float)*reinterpret_cast<const _Float16*>(
            P + (size_t)b * N3PAD + i);
#pragma unroll
        for (int e = 0; e < E_EXP; ++e) s += bl[e] * bias[e * D3 + i];
        v[n] = s; mx = fmaxf(mx, s); ++n;
    }
#pragma unroll
    for (int off = 32; off >= 1; off >>= 1) mx = fmaxf(mx, __shfl_xor(mx, off, 64));
    __shared__ float sm[4];
    if (lane == 0) sm[w] = mx;
    __syncthreads();
    mx = fmaxf(sm[0], sm[1]);
    float s = 0.f;
    for (int jj = 0; jj < n; ++jj) { v[jj] = expf(v[jj] - mx); s += v[jj]; }
#pragma unroll
    for (int off = 32; off >= 1; off >>= 1) s += __shfl_xor(s, off, 64);
    if (lane == 0) sm[2 + w] = s;
    __syncthreads();
    float inv = 1.f / (sm[2] + sm[3]);
    n = 0;
    for (int i = tid; i < D3; i += 128) { out[(size_t)b * D3 + i] = v[n] * inv; ++n; }
}

extern "C" void kernel_launch(void* const* d_in, const int* in_sizes, int n_in,
                              void* d_out, int out_size, void* d_ws, size_t ws_size,
                              hipStream_t stream) {
    const float* x = (const float*)d_in[0];
    const float* blend = (const float*)d_in[1];
    const float* W1 = (const float*)d_in[2];
    const float* b1 = (const float*)d_in[3];
    const float* W2 = (const float*)d_in[4];
    const float* b2 = (const float*)d_in[5];
    const float* W3 = (const float*)d_in[6];
    const float* b3 = (const float*)d_in[7];
    float* outp = (float*)d_out;

    char* ws = (char*)d_ws;
    u16* wf1 = (u16*)ws; ws += (size_t)E_EXP * 512 * KP * 2;    // 4.19 MB
    u16* wf2 = (u16*)ws; ws += (size_t)E_EXP * 512 * KP * 2;    // 4.19 MB
    u16* wf3 = (u16*)ws; ws += (size_t)E_EXP * N3PAD * KP * 2;  // 3.15 MB
    u16* xp = (u16*)ws;  ws += (size_t)BATCH * KP * 2;          // 8.39 MB
    u16* h1 = (u16*)ws;  ws += (size_t)BATCH * KP * 2;          // 8.39 MB
    u16* h2 = (u16*)ws;  ws += (size_t)BATCH * KP * 2;          // 8.39 MB
    u16* P = (u16*)ws;                                          // 8192*512*2 = 8.39 MB

    pack_all<<<1024, 256, 0, stream>>>(W1, W2, W3, wf1, wf2, wf3);
    pad_x<<<2048, 256, 0, stream>>>(x, xp);

    gemm_all<<<32 * 8, 512, 0, stream>>>(xp, wf1, blend, P, 512, 8);
    combine_h<<<BATCH / 4, 256, 0, stream>>>(P, blend, b1, h1);
    gemm_all<<<32 * 8, 512, 0, stream>>>(h1, wf2, blend, P, 512, 8);
    combine_h<<<BATCH / 4, 256, 0, stream>>>(P, blend, b2, h2);
    gemm_all<<<32 * 6, 512, 0, stream>>>(h2, wf3, blend, P, N3PAD, 6);
    combine_softmax<<<BATCH, 128, 0, stream>>>(P, blend, b3, outp);
}

// Round 10
// 220.185 us; speedup vs baseline: 3.3664x; 1.0048x over previous
//
#include <hip/hip_runtime.h>
#include <cstdint>

#define E_EXP 8
#define BATCH 8192
#define D0 480
#define D1 512
#define D2 512
#define D3 363
#define KP 512      // padded per-expert K
#define N3PAD 384

typedef _Float16 f16x8 __attribute__((ext_vector_type(8)));
typedef float f32x4 __attribute__((ext_vector_type(4)));
typedef unsigned short u16;
typedef u16 u16x8 __attribute__((ext_vector_type(8)));

__device__ __forceinline__ u16 f2h(float f) {
    _Float16 h = (_Float16)f;
    return __builtin_bit_cast(u16, h);
}

// async global->LDS, 16B per lane; LDS dest = wave-uniform base + lane*16
__device__ __forceinline__ void async16(const u16* g, u16* s) {
    __builtin_amdgcn_global_load_lds(
        reinterpret_cast<const __attribute__((address_space(1))) void*>(
            reinterpret_cast<uintptr_t>(g)),
        reinterpret_cast<__attribute__((address_space(3))) void*>(
            reinterpret_cast<uintptr_t>(s)),
        16, 0, 0);
}

// W[e][o][i] fp32 -> wf[e][o][0..511] fp16, zero-padded in o (to OUTP) and i (to 512)
__device__ __forceinline__ void pack_seg(const float* __restrict__ src,
                                         u16* __restrict__ dst,
                                         int OUT_src, int OUTP, int IN_src) {
    int total = E_EXP * OUTP * 128;
    int in4 = IN_src >> 2;
    for (int idx = blockIdx.x * blockDim.x + threadIdx.x; idx < total;
         idx += gridDim.x * blockDim.x) {
        int e = idx / (OUTP * 128);
        int r = idx - e * OUTP * 128;
        int o = r >> 7;
        int k4 = r & 127;
        ushort4 w;
        if (o < OUT_src && k4 < in4) {
            const float4 v = *reinterpret_cast<const float4*>(
                src + ((size_t)e * OUT_src + o) * IN_src + (k4 << 2));
            w.x = f2h(v.x); w.y = f2h(v.y); w.z = f2h(v.z); w.w = f2h(v.w);
        } else {
            w.x = 0; w.y = 0; w.z = 0; w.w = 0;
        }
        *reinterpret_cast<ushort4*>(dst + ((size_t)e * OUTP + o) * KP + (k4 << 2)) = w;
    }
}

__global__ void pack_all(const float* __restrict__ W1, const float* __restrict__ W2,
                         const float* __restrict__ W3, u16* __restrict__ wf1,
                         u16* __restrict__ wf2, u16* __restrict__ wf3) {
    pack_seg(W1, wf1, 512, 512, D0);
    pack_seg(W2, wf2, 512, 512, D1);
    pack_seg(W3, wf3, D3, N3PAD, D2);
}

// x (8192x480 fp32) -> xp (8192x512 fp16, zero-padded)
__global__ void pad_x(const float* __restrict__ x, u16* __restrict__ xp) {
    int total = BATCH * 128;
    for (int idx = blockIdx.x * blockDim.x + threadIdx.x; idx < total;
         idx += gridDim.x * blockDim.x) {
        int b = idx >> 7, k4 = idx & 127;
        ushort4 w;
        if (k4 < 120) {
            const float4 v = *reinterpret_cast<const float4*>(
                x + (size_t)b * D0 + (k4 << 2));
            w.x = f2h(v.x); w.y = f2h(v.y); w.z = f2h(v.z); w.w = f2h(v.w);
        } else {
            w.x = 0; w.y = 0; w.z = 0; w.w = 0;
        }
        *reinterpret_cast<ushort4*>(xp + (size_t)b * KP + (k4 << 2)) = w;
    }
}

// All-expert fused blended GEMM + fused epilogue:
//   acc[m][n] = sum_e bl[e,m] * (A @ W_e^T)[m,n]        (in-register blend on A)
//   out[m][n] = mode0: elu(acc + blended_bias) fp16     (next-layer h)
//               mode1: acc + blended_bias       fp16    (logits for softmax)
// Tile 256x64, BK=64, 8 barrier passes. 512 thr = 8 waves (4m x 2n).
// Grid 32*nbn, 1 block/CU, XCD key on bm (A-stream + B k-window L2-resident).
__global__ __launch_bounds__(512, 2) void gemm_all(
    const u16* __restrict__ A, const u16* __restrict__ Bw,
    const float* __restrict__ blend, const float* __restrict__ bias,
    u16* __restrict__ out, int OUTP, int OUTR, int nbn, int mode) {
    __shared__ __align__(16) u16 As[16384];  // 32 KB: 256 m-rows x 64 k
    __shared__ __align__(16) u16 Bs[32768];  // 64 KB: 8 e x 64 n x 64 k
    const int tid = threadIdx.x;
    const int w = tid >> 6, lane = tid & 63;
    const int wm2 = w & 3, wn2 = w >> 2;
    const int q = lane >> 4, l15 = lane & 15;

    const int id = blockIdx.x;
    const int xcd = id & 7;
    const int j = id >> 3;
    const int bm = ((j & 3) << 3) + xcd;  // 0..31 (256-row tiles), pinned to XCD
    const int bn = j >> 2;                // 0..nbn-1

    f32x4 acc[4][2];
#pragma unroll
    for (int mi = 0; mi < 4; ++mi)
#pragma unroll
        for (int ni = 0; ni < 2; ++ni) acc[mi][ni] = (f32x4){0.f, 0.f, 0.f, 0.f};

    // per-lane blend scalars: blh[e][mi] = blend[e, bm*256 + wm2*64 + mi*16 + l15]
    _Float16 blh[8][4];
#pragma unroll
    for (int e = 0; e < 8; ++e)
#pragma unroll
        for (int mi = 0; mi < 4; ++mi)
            blh[e][mi] = (_Float16)blend[e * BATCH + bm * 256 + wm2 * 64 +
                                         mi * 16 + l15];

    const int l8 = lane & 7, h8 = lane >> 3;
    const int c8 = (l8 ^ h8) << 3;  // XOR-swizzled k source offset
    const size_t EST = (size_t)OUTP * KP;  // expert stride in Bw
    // wave w stages A rows [w*32, w*32+32) and all 64 n-rows of expert e=w
    const u16* gA = A + (size_t)(bm * 256 + w * 32 + h8) * KP + c8;
    const u16* gB = Bw + (size_t)w * EST + (size_t)(bn * 64 + h8) * KP + c8;
    u16* sA = As + w * 2048;
    u16* sB = Bs + w * 4096;

    for (int kt = 0; kt < 8; ++kt) {
        const int ko = kt * 64;
#pragma unroll
        for (int u = 0; u < 4; ++u)
            async16(gA + (size_t)u * 8 * KP + ko, sA + u * 512);
#pragma unroll
        for (int u = 0; u < 8; ++u)
            async16(gB + (size_t)u * 8 * KP + ko, sB + u * 512);
        __syncthreads();
#pragma unroll
        for (int ks = 0; ks < 2; ++ks) {
            const int cs = (((q ^ (l15 & 7)) << 3) ^ (ks << 5));
            f16x8 af[4];
#pragma unroll
            for (int mi = 0; mi < 4; ++mi)
                af[mi] = *reinterpret_cast<const f16x8*>(
                    &As[(wm2 * 64 + mi * 16 + l15) * 64 + cs]);
#pragma unroll
            for (int e = 0; e < 8; ++e) {
                f16x8 bf0 = *reinterpret_cast<const f16x8*>(
                    &Bs[e * 4096 + (wn2 * 32 + l15) * 64 + cs]);
                f16x8 bf1 = *reinterpret_cast<const f16x8*>(
                    &Bs[e * 4096 + (wn2 * 32 + 16 + l15) * 64 + cs]);
#pragma unroll
                for (int mi = 0; mi < 4; ++mi) {
                    f16x8 as = af[mi] * blh[e][mi];
                    acc[mi][0] = __builtin_amdgcn_mfma_f32_16x16x32_f16(
                        as, bf0, acc[mi][0], 0, 0, 0);
                    acc[mi][1] = __builtin_amdgcn_mfma_f32_16x16x32_f16(
                        as, bf1, acc[mi][1], 0, 0, 0);
                }
            }
        }
        __syncthreads();
    }

    // fused epilogue: blended bias from LDS tiles, optional ELU, fp16 store
    float* Blf = reinterpret_cast<float*>(As);  // [256][8] blend[e, bm*256+r]
    float* Bif = reinterpret_cast<float*>(Bs);  // [64][8]  bias[e, bn*64+c]
    for (int idx = tid; idx < 2048; idx += 512) {
        int e = idx >> 8, r = idx & 255;
        Blf[r * 8 + e] = blend[e * BATCH + bm * 256 + r];
    }
    {
        int e = tid >> 6, c = tid & 63;
        int cg = bn * 64 + c;
        Bif[c * 8 + e] = (cg < OUTR) ? bias[e * OUTR + cg] : 0.f;
    }
    __syncthreads();
#pragma unroll
    for (int mi = 0; mi < 4; ++mi) {
#pragma unroll
        for (int ni = 0; ni < 2; ++ni) {
            int col_l = wn2 * 32 + ni * 16 + l15;
            int gcol = bn * 64 + col_l;
#pragma unroll
            for (int r = 0; r < 4; ++r) {
                int rl = wm2 * 64 + mi * 16 + q * 4 + r;
                float bb = 0.f;
#pragma unroll
                for (int e = 0; e < 8; ++e)
                    bb += Blf[rl * 8 + e] * Bif[col_l * 8 + e];
                float v = acc[mi][ni][r] + bb;
                if (mode == 0) v = v > 0.f ? v : expm1f(v);
                out[(size_t)(bm * 256 + rl) * OUTP + gcol] = f2h(v);
            }
        }
    }
}

// softmax over D3=363 of fp16 logits (bias already applied) -> fp32 out.
__global__ __launch_bounds__(128) void softmax_rows(
    const u16* __restrict__ P, float* __restrict__ out) {
    const int b = blockIdx.x;
    const int tid = threadIdx.x, lane = tid & 63, w = tid >> 6;
    float v[3];
    int n = 0;
    float mx = -3.4e38f;
    for (int i = tid; i < D3; i += 128) {
        float s = (float)*reinterpret_cast<const _Float16*>(
            P + (size_t)b * N3PAD + i);
        v[n] = s; mx = fmaxf(mx, s); ++n;
    }
#pragma unroll
    for (int off = 32; off >= 1; off >>= 1) mx = fmaxf(mx, __shfl_xor(mx, off, 64));
    __shared__ float sm[4];
    if (lane == 0) sm[w] = mx;
    __syncthreads();
    mx = fmaxf(sm[0], sm[1]);
    float s = 0.f;
    for (int jj = 0; jj < n; ++jj) { v[jj] = expf(v[jj] - mx); s += v[jj]; }
#pragma unroll
    for (int off = 32; off >= 1; off >>= 1) s += __shfl_xor(s, off, 64);
    if (lane == 0) sm[2 + w] = s;
    __syncthreads();
    float inv = 1.f / (sm[2] + sm[3]);
    n = 0;
    for (int i = tid; i < D3; i += 128) { out[(size_t)b * D3 + i] = v[n] * inv; ++n; }
}

extern "C" void kernel_launch(void* const* d_in, const int* in_sizes, int n_in,
                              void* d_out, int out_size, void* d_ws, size_t ws_size,
                              hipStream_t stream) {
    const float* x = (const float*)d_in[0];
    const float* blend = (const float*)d_in[1];
    const float* W1 = (const float*)d_in[2];
    const float* b1 = (const float*)d_in[3];
    const float* W2 = (const float*)d_in[4];
    const float* b2 = (const float*)d_in[5];
    const float* W3 = (const float*)d_in[6];
    const float* b3 = (const float*)d_in[7];
    float* outp = (float*)d_out;

    char* ws = (char*)d_ws;
    u16* wf1 = (u16*)ws; ws += (size_t)E_EXP * 512 * KP * 2;    // 4.19 MB
    u16* wf2 = (u16*)ws; ws += (size_t)E_EXP * 512 * KP * 2;    // 4.19 MB
    u16* wf3 = (u16*)ws; ws += (size_t)E_EXP * N3PAD * KP * 2;  // 3.15 MB
    u16* xp = (u16*)ws;  ws += (size_t)BATCH * KP * 2;          // 8.39 MB
    u16* h1 = (u16*)ws;  ws += (size_t)BATCH * KP * 2;          // 8.39 MB
    u16* h2 = (u16*)ws;  ws += (size_t)BATCH * KP * 2;          // 8.39 MB
    u16* P = (u16*)ws;                                          // 8192*384*2 = 6.29 MB

    pack_all<<<1024, 256, 0, stream>>>(W1, W2, W3, wf1, wf2, wf3);
    pad_x<<<2048, 256, 0, stream>>>(x, xp);

    gemm_all<<<32 * 8, 512, 0, stream>>>(xp, wf1, blend, b1, h1, 512, 512, 8, 0);
    gemm_all<<<32 * 8, 512, 0, stream>>>(h1, wf2, blend, b2, h2, 512, 512, 8, 0);
    gemm_all<<<32 * 6, 512, 0, stream>>>(h2, wf3, blend, b3, P, N3PAD, D3, 6, 1);
    softmax_rows<<<BATCH, 128, 0, stream>>>(P, outp);
}

// Round 11
// 212.066 us; speedup vs baseline: 3.4953x; 1.0383x over previous
//
#include <hip/hip_runtime.h>
#include <cstdint>

#define E_EXP 8
#define BATCH 8192
#define D0 480
#define D1 512
#define D2 512
#define D3 363
#define KP 512      // padded per-expert K
#define N3PAD 384

typedef _Float16 f16x8 __attribute__((ext_vector_type(8)));
typedef float f32x4 __attribute__((ext_vector_type(4)));
typedef unsigned short u16;
typedef u16 u16x8 __attribute__((ext_vector_type(8)));

__device__ __forceinline__ u16 f2h(float f) {
    _Float16 h = (_Float16)f;
    return __builtin_bit_cast(u16, h);
}

// async global->LDS, 16B per lane; LDS dest = wave-uniform base + lane*16
__device__ __forceinline__ void async16(const u16* g, u16* s) {
    __builtin_amdgcn_global_load_lds(
        reinterpret_cast<const __attribute__((address_space(1))) void*>(
            reinterpret_cast<uintptr_t>(g)),
        reinterpret_cast<__attribute__((address_space(3))) void*>(
            reinterpret_cast<uintptr_t>(s)),
        16, 0, 0);
}

// W[e][o][i] fp32 -> wf[e][o][0..511] fp16, zero-padded in o (to OUTP) and i (to 512)
__device__ __forceinline__ void pack_seg(const float* __restrict__ src,
                                         u16* __restrict__ dst,
                                         int OUT_src, int OUTP, int IN_src) {
    int total = E_EXP * OUTP * 128;
    int in4 = IN_src >> 2;
    for (int idx = blockIdx.x * blockDim.x + threadIdx.x; idx < total;
         idx += gridDim.x * blockDim.x) {
        int e = idx / (OUTP * 128);
        int r = idx - e * OUTP * 128;
        int o = r >> 7;
        int k4 = r & 127;
        ushort4 w;
        if (o < OUT_src && k4 < in4) {
            const float4 v = *reinterpret_cast<const float4*>(
                src + ((size_t)e * OUT_src + o) * IN_src + (k4 << 2));
            w.x = f2h(v.x); w.y = f2h(v.y); w.z = f2h(v.z); w.w = f2h(v.w);
        } else {
            w.x = 0; w.y = 0; w.z = 0; w.w = 0;
        }
        *reinterpret_cast<ushort4*>(dst + ((size_t)e * OUTP + o) * KP + (k4 << 2)) = w;
    }
}

__global__ void pack_all(const float* __restrict__ W1, const float* __restrict__ W2,
                         const float* __restrict__ W3, u16* __restrict__ wf1,
                         u16* __restrict__ wf2, u16* __restrict__ wf3) {
    pack_seg(W1, wf1, 512, 512, D0);
    pack_seg(W2, wf2, 512, 512, D1);
    pack_seg(W3, wf3, D3, N3PAD, D2);
}

// x (8192x480 fp32) -> xp (8192x512 fp16, zero-padded)
__global__ void pad_x(const float* __restrict__ x, u16* __restrict__ xp) {
    int total = BATCH * 128;
    for (int idx = blockIdx.x * blockDim.x + threadIdx.x; idx < total;
         idx += gridDim.x * blockDim.x) {
        int b = idx >> 7, k4 = idx & 127;
        ushort4 w;
        if (k4 < 120) {
            const float4 v = *reinterpret_cast<const float4*>(
                x + (size_t)b * D0 + (k4 << 2));
            w.x = f2h(v.x); w.y = f2h(v.y); w.z = f2h(v.z); w.w = f2h(v.w);
        } else {
            w.x = 0; w.y = 0; w.z = 0; w.w = 0;
        }
        *reinterpret_cast<ushort4*>(xp + (size_t)b * KP + (k4 << 2)) = w;
    }
}

// All-expert fused blended GEMM, DOUBLE-BUFFERED (BK=32, 16 passes):
//   acc[m][n] = sum_e bl[e,m] * (A @ W_e^T)[m,n]   (in-register blend on A)
//   out = mode0: elu(acc+blended_bias) fp16 (next h); mode1: acc+bias fp16 logits
// Tile 256x64; per 48KB buffer: As 256x32 + Bs 8e x 64n x 32k; 2 buffers = 96KB.
// Prefetch pass kt+1 issued BEFORE compute of pass kt -> drain at barrier is
// covered by ~1.5k cycles of MFMA. 512 thr = 8 waves (4m x 2n). Grid 32*nbn,
// 1 block/CU, XCD key on bm.
__global__ __launch_bounds__(512, 2) void gemm_all(
    const u16* __restrict__ A, const u16* __restrict__ Bw,
    const float* __restrict__ blend, const float* __restrict__ bias,
    u16* __restrict__ out, int OUTP, int OUTR, int nbn, int mode) {
    __shared__ __align__(16) u16 S[49152];  // 96 KB = 2 x (As 8192 + Bs 16384)
    const int tid = threadIdx.x;
    const int w = tid >> 6, lane = tid & 63;
    const int wm2 = w & 3, wn2 = w >> 2;
    const int q = lane >> 4, l15 = lane & 15;

    const int id = blockIdx.x;
    const int xcd = id & 7;
    const int j = id >> 3;
    const int bm = ((j & 3) << 3) + xcd;  // 0..31 (256-row tiles), pinned to XCD
    const int bn = j >> 2;                // 0..nbn-1

    f32x4 acc[4][2];
#pragma unroll
    for (int mi = 0; mi < 4; ++mi)
#pragma unroll
        for (int ni = 0; ni < 2; ++ni) acc[mi][ni] = (f32x4){0.f, 0.f, 0.f, 0.f};

    // per-lane blend scalars: blh[e][mi] = blend[e, bm*256 + wm2*64 + mi*16 + l15]
    _Float16 blh[8][4];
#pragma unroll
    for (int e = 0; e < 8; ++e)
#pragma unroll
        for (int mi = 0; mi < 4; ++mi)
            blh[e][mi] = (_Float16)blend[e * BATCH + bm * 256 + wm2 * 64 +
                                         mi * 16 + l15];

    // staging geometry: 1KB chunk = 16 rows x 32k; lane = r*4 + s
    const int l4r = lane >> 2;                 // row in chunk
    const int l4s = lane & 3;                  // phys slot
    const int ks8 = (l4s ^ (l4r & 3)) << 3;    // swizzled k elem offset
    const size_t EST = (size_t)OUTP * KP;      // expert stride in Bw
    const u16* gA0 = A + (size_t)(bm * 256 + w * 32 + l4r) * KP + ks8;
    const u16* gB0 = Bw + (size_t)w * EST + (size_t)(bn * 64 + l4r) * KP + ks8;
    const size_t R16 = (size_t)16 * KP;
    const int aBase = w * 1024;                // As dst (elems, within buffer)
    const int bBase = 8192 + w * 2048;         // Bs dst

    // fragment read offsets (loop-invariant)
    const int ra = (q ^ (l15 & 3)) << 3;       // swizzled k-slot for reads
    const int arow[4] = {(wm2 * 64 + 0 * 16 + l15) * 32 + ra,
                         (wm2 * 64 + 1 * 16 + l15) * 32 + ra,
                         (wm2 * 64 + 2 * 16 + l15) * 32 + ra,
                         (wm2 * 64 + 3 * 16 + l15) * 32 + ra};
    const int brow0 = (wn2 * 32 + l15) * 32 + ra;
    const int brow1 = (wn2 * 32 + 16 + l15) * 32 + ra;

    auto stage = [&](int kt, int p) {
        const int ko = kt << 5;
        u16* buf = S + p * 24576;
        async16(gA0 + ko, buf + aBase);
        async16(gA0 + R16 + ko, buf + aBase + 512);
        async16(gB0 + ko, buf + bBase);
        async16(gB0 + R16 + ko, buf + bBase + 512);
        async16(gB0 + 2 * R16 + ko, buf + bBase + 1024);
        async16(gB0 + 3 * R16 + ko, buf + bBase + 1536);
    };

    stage(0, 0);
    __syncthreads();

#pragma unroll 2
    for (int kt = 0; kt < 16; ++kt) {
        const int p = kt & 1;
        if (kt < 15) stage(kt + 1, p ^ 1);
        const u16* As_ = S + p * 24576;
        const u16* Bs_ = As_ + 8192;
        f16x8 af[4];
#pragma unroll
        for (int mi = 0; mi < 4; ++mi)
            af[mi] = *reinterpret_cast<const f16x8*>(&As_[arow[mi]]);
#pragma unroll
        for (int e = 0; e < 8; ++e) {
            f16x8 bf0 = *reinterpret_cast<const f16x8*>(&Bs_[e * 2048 + brow0]);
            f16x8 bf1 = *reinterpret_cast<const f16x8*>(&Bs_[e * 2048 + brow1]);
#pragma unroll
            for (int mi = 0; mi < 4; ++mi) {
                f16x8 as = af[mi] * blh[e][mi];
                acc[mi][0] = __builtin_amdgcn_mfma_f32_16x16x32_f16(
                    as, bf0, acc[mi][0], 0, 0, 0);
                acc[mi][1] = __builtin_amdgcn_mfma_f32_16x16x32_f16(
                    as, bf1, acc[mi][1], 0, 0, 0);
            }
        }
        __syncthreads();
    }

    // fused epilogue: blended bias from LDS tiles, optional ELU, fp16 store
    float* Blf = reinterpret_cast<float*>(S);           // [256][8]
    float* Bif = reinterpret_cast<float*>(S + 16384);   // [64][8] (32 KB in)
    for (int idx = tid; idx < 2048; idx += 512) {
        int e = idx >> 8, r = idx & 255;
        Blf[r * 8 + e] = blend[e * BATCH + bm * 256 + r];
    }
    {
        int e = tid >> 6, c = tid & 63;
        int cg = bn * 64 + c;
        Bif[c * 8 + e] = (cg < OUTR) ? bias[e * OUTR + cg] : 0.f;
    }
    __syncthreads();
#pragma unroll
    for (int mi = 0; mi < 4; ++mi) {
#pragma unroll
        for (int ni = 0; ni < 2; ++ni) {
            int col_l = wn2 * 32 + ni * 16 + l15;
            int gcol = bn * 64 + col_l;
#pragma unroll
            for (int r = 0; r < 4; ++r) {
                int rl = wm2 * 64 + mi * 16 + q * 4 + r;
                float bb = 0.f;
#pragma unroll
                for (int e = 0; e < 8; ++e)
                    bb += Blf[rl * 8 + e] * Bif[col_l * 8 + e];
                float v = acc[mi][ni][r] + bb;
                if (mode == 0) v = v > 0.f ? v : expm1f(v);
                out[(size_t)(bm * 256 + rl) * OUTP + gcol] = f2h(v);
            }
        }
    }
}

// softmax over D3=363 of fp16 logits (bias already applied) -> fp32 out.
__global__ __launch_bounds__(128) void softmax_rows(
    const u16* __restrict__ P, float* __restrict__ out) {
    const int b = blockIdx.x;
    const int tid = threadIdx.x, lane = tid & 63, w = tid >> 6;
    float v[3];
    int n = 0;
    float mx = -3.4e38f;
    for (int i = tid; i < D3; i += 128) {
        float s = (float)*reinterpret_cast<const _Float16*>(
            P + (size_t)b * N3PAD + i);
        v[n] = s; mx = fmaxf(mx, s); ++n;
    }
#pragma unroll
    for (int off = 32; off >= 1; off >>= 1) mx = fmaxf(mx, __shfl_xor(mx, off, 64));
    __shared__ float sm[4];
    if (lane == 0) sm[w] = mx;
    __syncthreads();
    mx = fmaxf(sm[0], sm[1]);
    float s = 0.f;
    for (int jj = 0; jj < n; ++jj) { v[jj] = expf(v[jj] - mx); s += v[jj]; }
#pragma unroll
    for (int off = 32; off >= 1; off >>= 1) s += __shfl_xor(s, off, 64);
    if (lane == 0) sm[2 + w] = s;
    __syncthreads();
    float inv = 1.f / (sm[2] + sm[3]);
    n = 0;
    for (int i = tid; i < D3; i += 128) { out[(size_t)b * D3 + i] = v[n] * inv; ++n; }
}

extern "C" void kernel_launch(void* const* d_in, const int* in_sizes, int n_in,
                              void* d_out, int out_size, void* d_ws, size_t ws_size,
                              hipStream_t stream) {
    const float* x = (const float*)d_in[0];
    const float* blend = (const float*)d_in[1];
    const float* W1 = (const float*)d_in[2];
    const float* b1 = (const float*)d_in[3];
    const float* W2 = (const float*)d_in[4];
    const float* b2 = (const float*)d_in[5];
    const float* W3 = (const float*)d_in[6];
    const float* b3 = (const float*)d_in[7];
    float* outp = (float*)d_out;

    char* ws = (char*)d_ws;
    u16* wf1 = (u16*)ws; ws += (size_t)E_EXP * 512 * KP * 2;    // 4.19 MB
    u16* wf2 = (u16*)ws; ws += (size_t)E_EXP * 512 * KP * 2;    // 4.19 MB
    u16* wf3 = (u16*)ws; ws += (size_t)E_EXP * N3PAD * KP * 2;  // 3.15 MB
    u16* xp = (u16*)ws;  ws += (size_t)BATCH * KP * 2;          // 8.39 MB
    u16* h1 = (u16*)ws;  ws += (size_t)BATCH * KP * 2;          // 8.39 MB
    u16* h2 = (u16*)ws;  ws += (size_t)BATCH * KP * 2;          // 8.39 MB
    u16* P = (u16*)ws;                                          // 8192*384*2 = 6.29 MB

    pack_all<<<1024, 256, 0, stream>>>(W1, W2, W3, wf1, wf2, wf3);
    pad_x<<<2048, 256, 0, stream>>>(x, xp);

    gemm_all<<<32 * 8, 512, 0, stream>>>(xp, wf1, blend, b1, h1, 512, 512, 8, 0);
    gemm_all<<<32 * 8, 512, 0, stream>>>(h1, wf2, blend, b2, h2, 512, 512, 8, 0);
    gemm_all<<<32 * 6, 512, 0, stream>>>(h2, wf3, blend, b3, P, N3PAD, D3, 6, 1);
    softmax_rows<<<BATCH, 128, 0, stream>>>(P, outp);
}